// Round 16
// baseline (684.304 us; speedup 1.0000x reference)
//
#include <hip/hip_runtime.h>
#include <hip/hip_bf16.h>

// ---------------------------------------------------------------------------
// VAE + supervised MoE forward, MI355X.
//   k_prep_enc: one-time bf16 dual-split pack of encoder conv2/conv3 weights
//               AND fc weight pack [w_mu|w_lv]
//   k_enc    : FUSED encoder conv1+conv2+conv3, one sample per block,
//              1024 threads / 16 waves (LDS 76.8KB -> 2 blocks/CU -> 32
//              waves/CU). Wave split keeps aggregate LDS A-traffic constant.
//              h1 RNE dual (h,h,m,0); h2 in LDS; h3 RNE dual-packed.
//   k_fc     : MFMA slot-split GEMM, LDS-free, K-split 8, partials into U
//   k_gate   : one wave per sample, lane-parallel, shfl softmax/argmax
//   k_prep   : decoder weight repack to bf16, FRAGMENT-LINEAR order
//   k_dfc    : z @ d_fc_w[e] + b -> hfcb bf16
//   k_dec    : FUSED decoder conv1+conv2+conv3, one sample per block
// ---------------------------------------------------------------------------

#define NB 2048

typedef short bf16x8 __attribute__((ext_vector_type(8)));
typedef float f32x4  __attribute__((ext_vector_type(4)));
typedef unsigned u32x4 __attribute__((ext_vector_type(4)));

static constexpr int OFF_RECON  = 0;
static constexpr int OFF_MU     = 1605632;
static constexpr int OFF_LV     = 1736704;
static constexpr int OFF_LOGITS = 1867776;
static constexpr int OFF_PROBS  = 1884160;

// workspace layout (float units)
static constexpr size_t WS_U    = 0;         // 25,690,112 fl (2048 x 12544)
static constexpr size_t WS_Z    = 25690112;  // 131,072 fl
static constexpr size_t WS_IDX  = 25821184;  // 2,048 ints = 512 fl
static constexpr size_t WS_WENC = 25821696;  // packed weights
static constexpr size_t W2S_OFF = 0;         // 36,864 fl
static constexpr size_t W3S_OFF = 36864;     // 147,456 fl
static constexpr size_t WFC_OFF = 184320;    // 802,816 fl (fc (h,m) pack)
static constexpr size_t HFC_OFF = 0;         // hfcb bf16 [n][49][32] in U
static constexpr size_t W1B_OFF = 17000448;  // U tail (written after k_gate)
static constexpr size_t WCB_OFF = 17074176;  // U tail

__device__ __forceinline__ float relu_f(float v) { return v > 0.f ? v : 0.f; }
// branchless ELU: exact for v>=0 (exp(0)==1), error ~3e-8 abs for tiny v<0
__device__ __forceinline__ float elu_f(float v)  {
  return __expf(fminf(v, 0.f)) - 1.f + fmaxf(v, 0.f);
}
__device__ __forceinline__ short f2b(float v) {
  __hip_bfloat16 h = __float2bfloat16(v);
  short s; __builtin_memcpy(&s, &h, 2); return s;
}
__device__ __forceinline__ float s2f(short s) {
  unsigned v = ((unsigned)(unsigned short)s) << 16;
  float f; __builtin_memcpy(&f, &v, 4); return f;
}
// RNE dual pack: v -> (h16 | m16<<16)
__device__ __forceinline__ unsigned pack2(float v) {
  short h = f2b(v);
  short m = f2b(v - s2f(h));
  return (unsigned)(unsigned short)h | ((unsigned)(unsigned short)m << 16);
}

// ---------------------------------------------------------------------------
// one-time weight packs (encoder + fc).
// ---------------------------------------------------------------------------
__global__ __launch_bounds__(256) void k_prep_enc(
    const float* __restrict__ ew2, const float* __restrict__ ew3,
    const float* __restrict__ wmu, const float* __restrict__ wlv,
    unsigned short* __restrict__ w2s, unsigned short* __restrict__ w3s,
    unsigned* __restrict__ wfc)
{
  const int u = blockIdx.x * 256 + threadIdx.x;
  if (u >= 894976) return;
  if (u >= 92160) {
    const int u2 = u - 92160;
    const int kp = u2 >> 8, r = u2 & 255;
    const int n = r >> 1, j = r & 1;
    const int k = kp * 2 + j;
    const float w = (n < 64) ? wmu[k * 64 + n] : wlv[k * 64 + (n - 64)];
    short h = f2b(w);
    short mm = f2b(w - s2f(h));
    wfc[u2] = (unsigned)(unsigned short)h | ((unsigned)(unsigned short)mm << 16);
    return;
  }
  float w; uint2* dst;
  if (u < 18432) {
    int ic = u & 7, oc = (u >> 3) & 63;
    int r = u >> 9;           // chunk*9 + tap
    int tap = r % 9, chunk = r / 9;
    w = ew2[oc * 288 + (chunk * 8 + ic) * 9 + tap];
    dst = (uint2*)w2s + u;
  } else {
    int u2 = u - 18432;
    int ic = u2 & 7, oc = (u2 >> 3) & 127;
    int r = u2 >> 10;         // chunk*9 + tap
    int tap = r % 9, chunk = r / 9;
    w = ew3[oc * 576 + (chunk * 8 + ic) * 9 + tap];
    dst = (uint2*)w3s + u2;
  }
  short h = f2b(w);
  short mm = f2b(w - s2f(h));
  uint2 pk;
  pk.x = (unsigned)(unsigned short)h | ((unsigned)(unsigned short)mm << 16);
  pk.y = (unsigned)(unsigned short)h | ((unsigned)(unsigned short)h << 16);
  *dst = pk;
}

// ---------------------------------------------------------------------------
// FUSED encoder, 1024 threads / 16 waves.
// conv2 wave = (mh 0..7, nth 0..1): mt = mh + 8*i (i<2), oc = nth*32+ntl*16.
// conv3 wave = (oct 0..7, mhalf 0..1): oc3 = oct*16, mt = mhalf*2 + i (i<2).
// Accumulation order per output unchanged -> bit-identical h2/h3.
// ---------------------------------------------------------------------------
__global__ __launch_bounds__(1024, 2) void k_enc(
    const float* __restrict__ x,
    const float* __restrict__ w1, const float* __restrict__ b1,
    const float* __restrict__ b2g, const unsigned short* __restrict__ w2s,
    const unsigned short* __restrict__ w3s, const float* __restrict__ b3,
    unsigned* __restrict__ hb)
{
  __shared__ float sX[900];
  __shared__ float sB2[64];
  __shared__ float sB3[128];
  __shared__ __align__(16) short sH[36000];   // 72,000 B union

  const int n = blockIdx.x, t = threadIdx.x;

  for (int idx = t; idx < 900; idx += 1024) {
    int yy = idx / 30, xx = idx % 30;
    float v = 0.f;
    if (yy >= 1 && yy <= 28 && xx >= 1 && xx <= 28)
      v = x[n * 784 + (yy - 1) * 28 + (xx - 1)];
    sX[idx] = v;
  }
  if (t < 64) sB2[t] = b2g[t];
  if (t >= 64 && t < 192) sB3[t - 64] = b3[t - 64];
  for (int bi = t; bi < 116; bi += 1024) {
    int p;
    if (bi < 30) p = bi;
    else if (bi < 60) p = 870 + (bi - 30);
    else if (bi < 88) p = (bi - 59) * 30;
    else p = (bi - 87) * 30 + 29;
    unsigned* d = (unsigned*)&sH[p * 40];
    #pragma unroll
    for (int j = 0; j < 20; ++j) d[j] = 0u;
  }
  __syncthreads();

  // conv1: one pixel per thread
  float xw[9];
  const bool pvld = (t < 784);
  int hp;
  {
    int p = pvld ? t : 0;
    int yy = p / 28, xx = p % 28;
    hp = (yy + 1) * 30 + xx + 1;
    #pragma unroll
    for (int k = 0; k < 9; ++k)
      xw[k] = sX[(yy + k / 3) * 30 + xx + (k % 3)];
  }

  const int lane = t & 63, wv = t >> 6;        // wv 0..15
  const int q = lane >> 4, m16 = lane & 15;
  const int nth = wv & 1, mh = wv >> 1;        // mh 0..7
  const int nm = (mh < 5) ? 2 : 1;             // mt = mh + 8*i <= 12

  int abase[2];
  #pragma unroll
  for (int mtl = 0; mtl < 2; ++mtl) {
    int m = (mh + 8 * mtl) * 16 + m16; if (m > 195) m = 195;
    int yy = m / 14, xx = m % 14;
    abase[mtl] = (yy * 60 + xx * 2) * 40 + q * 8;
  }
  f32x4 acc[2][2];
  #pragma unroll
  for (int a = 0; a < 2; ++a) { acc[a][0] = (f32x4)0.f; acc[a][1] = (f32x4)0.f; }

  // ---- conv1 + conv2 (4 ic-chunks). h1 RNE dual-split (h,h,m,0). ----
  for (int c = 0; c < 4; ++c) {
    #pragma unroll
    for (int o = 0; o < 8; ++o) {
      const int oc = c * 8 + o;
      float wr[9];
      #pragma unroll
      for (int k = 0; k < 9; ++k) wr[k] = w1[oc * 9 + k];
      const float bb = b1[oc];
      if (pvld) {
        float v = bb;
        #pragma unroll
        for (int k = 0; k < 9; ++k) v += xw[k] * wr[k];
        v = relu_f(v);
        short h = f2b(v);
        short mm = f2b(v - s2f(h));
        uint2 pk;
        pk.x = (unsigned)(unsigned short)h | ((unsigned)(unsigned short)h << 16);
        pk.y = (unsigned)(unsigned short)mm;
        *(uint2*)&sH[hp * 40 + o * 4] = pk;
      }
    }
    __syncthreads();

    const unsigned short* wb = w2s + (size_t)c * 18432;
    for (int tap = 0; tap < 9; ++tap) {
      const int toff = ((tap / 3) * 30 + (tap % 3)) * 40;
      bf16x8 A[2];
      #pragma unroll
      for (int mtl = 0; mtl < 2; ++mtl)
        A[mtl] = *(const bf16x8*)&sH[abase[mtl] + toff];
      #pragma unroll
      for (int ntl = 0; ntl < 2; ++ntl) {
        const int ocl = nth * 32 + ntl * 16 + m16;
        bf16x8 B = *(const bf16x8*)&wb[(tap * 64 + ocl) * 32 + q * 8];
        #pragma unroll
        for (int mtl = 0; mtl < 2; ++mtl)
          if (mtl < nm)
            acc[mtl][ntl] = __builtin_amdgcn_mfma_f32_16x16x32_bf16(A[mtl], B, acc[mtl][ntl], 0, 0, 0);
      }
    }
    __syncthreads();
  }

  // ---- h2 -> LDS packed [196][65] (reuses sH); zero conv3 sIn borders ----
  unsigned* h2p = (unsigned*)sH;
  short* sIn = sH + 25600;
  #pragma unroll
  for (int mtl = 0; mtl < 2; ++mtl) {
    if (mtl < nm) {
      const int mt = mh + 8 * mtl;
      #pragma unroll
      for (int ntl = 0; ntl < 2; ++ntl) {
        const int oc = nth * 32 + ntl * 16 + m16;
        const float bb = sB2[oc];
        #pragma unroll
        for (int r = 0; r < 4; ++r) {
          int p = mt * 16 + q * 4 + r;
          if (p < 196)
            h2p[p * 65 + oc] = pack2(relu_f(acc[mtl][ntl][r] + bb));
        }
      }
    }
  }
  for (int bi = t; bi < 60; bi += 1024) {
    int p;
    if (bi < 16) p = bi;
    else if (bi < 32) p = 240 + (bi - 16);
    else if (bi < 46) p = (bi - 31) * 16;
    else p = (bi - 45) * 16 + 15;
    unsigned* d = (unsigned*)&sIn[p * 40];
    #pragma unroll
    for (int j = 0; j < 20; ++j) d[j] = 0u;
  }

  // ---- conv3: 8 ic-chunks. wave = (oct 0..7, mhalf 0..1), 2 m-tiles ----
  const int oc3 = (wv & 7) * 16 + m16;
  const int mhalf = wv >> 3;
  int abase3[2];
  #pragma unroll
  for (int i = 0; i < 2; ++i) {
    int m = (mhalf * 2 + i) * 16 + m16; if (m > 48) m = 48;
    int yy = m / 7, xx = m % 7;
    abase3[i] = (yy * 32 + xx * 2) * 40 + q * 8;
  }
  f32x4 acc3[2];
  acc3[0] = (f32x4)0.f; acc3[1] = (f32x4)0.f;

  for (int c = 0; c < 8; ++c) {
    __syncthreads();
    if (t < 784) {
      int pix = t >> 2, icq = t & 3;     // ic pair icq*2, icq*2+1
      int rr = pix / 14 + 1, cc = pix % 14 + 1;
      short* drow = &sIn[(rr * 16 + cc) * 40 + icq * 8];
      #pragma unroll
      for (int i = 0; i < 2; ++i) {
        unsigned u = h2p[pix * 65 + c * 8 + icq * 2 + i];   // h16 | m16<<16
        uint2 pk;
        pk.x = (u << 16) | (u & 0xffffu);                 // (low=h, high=h)
        pk.y = u >> 16;                                   // (low=m, high=0)
        *(uint2*)&drow[i * 4] = pk;
      }
    }
    __syncthreads();

    const unsigned short* wc = w3s + (size_t)c * 36864;
    for (int tap = 0; tap < 9; ++tap) {
      const int toff = ((tap / 3) * 16 + (tap % 3)) * 40;
      bf16x8 B = *(const bf16x8*)&wc[(tap * 128 + oc3) * 32 + q * 8];
      #pragma unroll
      for (int i = 0; i < 2; ++i) {
        bf16x8 A = *(const bf16x8*)&sIn[abase3[i] + toff];
        acc3[i] = __builtin_amdgcn_mfma_f32_16x16x32_bf16(A, B, acc3[i], 0, 0, 0);
      }
    }
  }

  // ---- h3 epilogue: relu + RNE dual pack -> global ----
  const float bb3 = sB3[oc3];
  #pragma unroll
  for (int i = 0; i < 2; ++i) {
    const int mt = mhalf * 2 + i;
    #pragma unroll
    for (int r = 0; r < 4; ++r) {
      int m = mt * 16 + q * 4 + r;
      if (m < 49)
        hb[(size_t)n * 12544 + oc3 * 49 + m] = pack2(relu_f(acc3[i][r] + bb3));
    }
  }
}

// ---------------------------------------------------------------------------
// fc via slot-split MFMA, LDS-free. K-split 8, partials into U upper halves.
// ---------------------------------------------------------------------------
__global__ __launch_bounds__(256) void k_fc(
    const unsigned* __restrict__ A2,
    const unsigned* __restrict__ wfc,
    float* __restrict__ Uf)
{
  const int t = threadIdx.x;
  const int lane = t & 63, wv = t >> 6;
  const int q = lane >> 4, m16 = lane & 15;
  const int m0 = blockIdx.x * 64;
  const int s  = blockIdx.y;

  const unsigned* arow[4];
  #pragma unroll
  for (int mt = 0; mt < 4; ++mt)
    arow[mt] = A2 + (size_t)(m0 + mt * 16 + m16) * 12544 + s * 784 + 2 * q;
  const unsigned* brow[2];
  #pragma unroll
  for (int ntl = 0; ntl < 2; ++ntl)
    brow[ntl] = wfc + (size_t)(s * 392 + q) * 256 + ((wv * 2 + ntl) * 16 + m16) * 2;

  f32x4 acc[4][2];
  #pragma unroll
  for (int a = 0; a < 4; ++a) { acc[a][0] = (f32x4)0.f; acc[a][1] = (f32x4)0.f; }

  #pragma unroll 2
  for (int kt = 0; kt < 98; ++kt) {
    bf16x8 Af[4];
    #pragma unroll
    for (int mt = 0; mt < 4; ++mt) {
      uint2 u = *(const uint2*)(arow[mt] + kt * 8);
      u32x4 w = { (u.x << 16) | (u.x & 0xffffu), u.x >> 16,
                  (u.y << 16) | (u.y & 0xffffu), u.y >> 16 };
      Af[mt] = __builtin_bit_cast(bf16x8, w);
    }
    #pragma unroll
    for (int ntl = 0; ntl < 2; ++ntl) {
      uint2 u = *(const uint2*)(brow[ntl] + kt * 1024);
      u32x4 w = { u.x, (u.x << 16) | (u.x & 0xffffu),
                  u.y, (u.y << 16) | (u.y & 0xffffu) };
      bf16x8 Bf = __builtin_bit_cast(bf16x8, w);
      #pragma unroll
      for (int mt = 0; mt < 4; ++mt)
        acc[mt][ntl] = __builtin_amdgcn_mfma_f32_16x16x32_bf16(Af[mt], Bf, acc[mt][ntl], 0, 0, 0);
    }
  }

  #pragma unroll
  for (int mt = 0; mt < 4; ++mt) {
    #pragma unroll
    for (int ntl = 0; ntl < 2; ++ntl) {
      const int n = (wv * 2 + ntl) * 16 + m16;
      #pragma unroll
      for (int r = 0; r < 4; ++r) {
        const int row = m0 + mt * 16 + q * 4 + r;
        Uf[(size_t)row * 12544 + 6272 + s * 128 + n] = acc[mt][ntl][r];
      }
    }
  }
}

// ---------------------------------------------------------------------------
// gate (fp32), ONE WAVE PER SAMPLE. 512 blocks x 256 threads (4 waves).
// ---------------------------------------------------------------------------
__global__ __launch_bounds__(256) void k_gate(
    const float* __restrict__ Ubase,
    const float* __restrict__ b_mu, const float* __restrict__ b_lv,
    const float* __restrict__ eps,
    const float* __restrict__ gw1, const float* __restrict__ gb1,
    const float* __restrict__ gw2, const float* __restrict__ gb2,
    const float* __restrict__ gw3, const float* __restrict__ gb3,
    float* __restrict__ out, float* __restrict__ zbuf, int* __restrict__ idxbuf)
{
  __shared__ float sZ[4][64];
  __shared__ float sG1[4][64];
  __shared__ float sG2[4][32];
  const int t = threadIdx.x;
  const int wv = t >> 6, lane = t & 63;
  const int m = blockIdx.x * 4 + wv;
  const float* __restrict__ Up = Ubase + (size_t)m * 12544 + 6272;

  {
    const int k = lane;
    float mu = b_mu[k], lv = b_lv[k];
    #pragma unroll
    for (int s8 = 0; s8 < 8; ++s8) {
      mu += Up[s8 * 128 + k];
      lv += Up[s8 * 128 + 64 + k];
    }
    out[OFF_MU + m * 64 + k] = mu;
    out[OFF_LV + m * 64 + k] = lv;
    float zz = mu + eps[m * 64 + k] * expf(0.5f * lv);
    sZ[wv][k] = zz;
    zbuf[m * 64 + k] = zz;
  }

  {
    const int j = lane;
    float a = gb1[j];
    for (int k = 0; k < 64; ++k) a += sZ[wv][k] * gw1[k * 64 + j];
    sG1[wv][j] = relu_f(a);
  }
  if (lane < 32) {
    const int j = lane;
    float a = gb2[j];
    for (int k = 0; k < 64; ++k) a += sG1[wv][k] * gw2[k * 32 + j];
    sG2[wv][j] = relu_f(a);
  }
  float l = -1e30f;
  if (lane < 8) {
    float a = gb3[lane];
    for (int k = 0; k < 32; ++k) a += sG2[wv][k] * gw3[k * 8 + lane];
    l = a;
  }
  float mx = l;
  #pragma unroll
  for (int off = 4; off; off >>= 1) mx = fmaxf(mx, __shfl_xor(mx, off, 8));
  float p = expf(l - mx);
  float ssum = p;
  #pragma unroll
  for (int off = 4; off; off >>= 1) ssum += __shfl_xor(ssum, off, 8);
  float pj = p / ssum;
  if (lane < 8) {
    out[OFF_PROBS + m * 8 + lane] = pj;
    out[OFF_LOGITS + m * 8 + lane] = logf(pj + 1e-8f);
  }
  float pmax = pj;
  #pragma unroll
  for (int off = 4; off; off >>= 1) pmax = fmaxf(pmax, __shfl_xor(pmax, off, 8));
  unsigned long long msk = __ballot(lane < 8 && pj == pmax);
  if (lane == 0) idxbuf[m] = __ffsll(msk) - 1;
}

// ---------------------------------------------------------------------------
// one-time decoder weight repack to bf16, FRAGMENT-LINEAR order.
// ---------------------------------------------------------------------------
__global__ __launch_bounds__(256) void k_prep(
    const float* __restrict__ dw1, const float* __restrict__ dw2,
    unsigned short* __restrict__ w1b, unsigned short* __restrict__ wcb)
{
  const int e = blockIdx.x, job = blockIdx.y, t = threadIdx.x;
  if (job == 0) {
    for (int idx = t; idx < 18432; idx += 256) {
      int tap = idx >> 11;
      int rem = idx & 2047;
      int octile = rem >> 9;
      int lane = (rem >> 3) & 63;
      int j = idx & 7;
      int oc = octile * 16 + (lane & 15);
      int ic = (lane >> 4) * 8 + j;
      w1b[(size_t)e * 18432 + idx] =
          (unsigned short)f2b(dw1[(size_t)e * 18432 + (oc * 32 + ic) * 9 + tap]);
    }
  } else {
    const int par = job - 1, py = par >> 1, px = par & 1;
    for (int v = t; v < 8192; v += 256) {
      int s = v >> 10;
      int nt = (v >> 9) & 1;
      int lane = (v >> 3) & 63;
      int j = v & 7;
      int oc = nt * 16 + (lane & 15);
      int tap = s >> 1, h = s & 1;
      int ty = tap >> 1, tx = tap & 1;
      int icg = h * 32 + (lane >> 4) * 8 + j;
      int ys = (ty == 0) ? 0 : (1 + py);
      int yc = (ty == py) ? 1 : 2;
      int xs = (tx == 0) ? 0 : (1 + px);
      int xc = (tx == px) ? 1 : 2;
      const float* wp = &dw2[(size_t)e * 18432 + (oc * 64 + icg) * 9];
      float a = 0.f;
      for (int ky = ys; ky < ys + yc; ++ky)
        for (int kx = xs; kx < xs + xc; ++kx)
          a += wp[ky * 3 + kx];
      wcb[((size_t)e * 4 + par) * 8192 + v] = (unsigned short)f2b(a);
    }
  }
}

// ---------------------------------------------------------------------------
// decoder fc: z[64] @ d_fc_w[e][64][1568] + b -> hfcb bf16 [n][pix49][ic32]
// ---------------------------------------------------------------------------
__global__ __launch_bounds__(256) void k_dfc(
    const float* __restrict__ zbuf, const int* __restrict__ idxbuf,
    const float* __restrict__ fcw, const float* __restrict__ fcb,
    unsigned* __restrict__ hfcb)
{
  __shared__ float sZ[64];
  __shared__ __align__(16) unsigned short sO[1568];
  const int n = blockIdx.x, t = threadIdx.x;
  const int e = idxbuf[n];
  if (t < 64) sZ[t] = zbuf[n * 64 + t];
  __syncthreads();
  const float* __restrict__ W = fcw + (size_t)e * 100352;
  const int i40 = t, i41 = t + 256;
  const bool v1 = (i41 < 392);
  float a0[4], a1[4];
  {
    float4 b0 = *(const float4*)&fcb[e * 1568 + i40 * 4];
    a0[0] = b0.x; a0[1] = b0.y; a0[2] = b0.z; a0[3] = b0.w;
    if (v1) {
      float4 b1v = *(const float4*)&fcb[e * 1568 + i41 * 4];
      a1[0] = b1v.x; a1[1] = b1v.y; a1[2] = b1v.z; a1[3] = b1v.w;
    } else { a1[0] = a1[1] = a1[2] = a1[3] = 0.f; }
  }
  for (int k = 0; k < 64; ++k) {
    const float zk = sZ[k];
    float4 w0 = *(const float4*)&W[k * 1568 + i40 * 4];
    a0[0] += zk * w0.x; a0[1] += zk * w0.y; a0[2] += zk * w0.z; a0[3] += zk * w0.w;
    if (v1) {
      float4 w1v = *(const float4*)&W[k * 1568 + i41 * 4];
      a1[0] += zk * w1v.x; a1[1] += zk * w1v.y; a1[2] += zk * w1v.z; a1[3] += zk * w1v.w;
    }
  }
  #pragma unroll
  for (int c = 0; c < 4; ++c) {
    int j = i40 * 4 + c;
    int ic = j / 49, p = j % 49;
    sO[p * 32 + ic] = (unsigned short)f2b(a0[c]);
  }
  if (v1) {
    #pragma unroll
    for (int c = 0; c < 4; ++c) {
      int j = i41 * 4 + c;
      int ic = j / 49, p = j % 49;
      sO[p * 32 + ic] = (unsigned short)f2b(a1[c]);
    }
  }
  __syncthreads();
  for (int idx = t; idx < 784; idx += 256)
    hfcb[(size_t)n * 784 + idx] = ((const unsigned*)sO)[idx];
}

// ---------------------------------------------------------------------------
// FUSED decoder: d1 + d23, one sample per block, 512 threads / 8 waves.
// ---------------------------------------------------------------------------
__global__ __launch_bounds__(512, 4) void k_dec(
    const unsigned* __restrict__ hfcb, const int* __restrict__ idxbuf,
    const unsigned* __restrict__ w1b, const float* __restrict__ db1,
    const unsigned* __restrict__ wcb, const float* __restrict__ b2,
    const float* __restrict__ w3, const float* __restrict__ b3,
    float* __restrict__ out)
{
  __shared__ __align__(16) short sPool[32712];
  __shared__ float sB1[64];
  __shared__ float sB2[32];

  short* sInH  = sPool;            // phase A input (256x40)
  short* sW    = sPool + 10240;    // phase A weights (9216 uints)
  short* sD1   = sPool + 10240;    // phase B haloed d1 output (256x72)
  short* sU    = sPool;            // phase B conv2 weights/act (8192 shorts)
  short* sW3b  = sPool + 28672;    // 512 shorts
  float* sC    = (float*)(sPool + 29184);  // 196*9 floats

  const int n = blockIdx.x, t = threadIdx.x;
  const int e = idxbuf[n];

  // ---- phase A staging ----
  {
    int cell = t >> 1, half = t & 1;
    int r = cell >> 4, c = cell & 15;
    bool inter = (r >= 1 && r <= 14 && c >= 1 && c <= 14);
    int src = inter ? (((r - 1) >> 1) * 7 + ((c - 1) >> 1)) : 0;
    const unsigned* hp = &hfcb[(size_t)n * 784 + src * 16 + half * 8];
    unsigned* dst = (unsigned*)&sInH[cell * 40] + half * 8;
    #pragma unroll
    for (int i = 0; i < 8; ++i) dst[i] = inter ? hp[i] : 0u;
  }
  {
    const unsigned* wsrc = w1b + (size_t)e * 9216;
    unsigned* wd = (unsigned*)sW;
    for (int idx = t; idx < 9216; idx += 512) wd[idx] = wsrc[idx];
  }
  {
    int nn = t >> 5, k = t & 31;
    if (t < 512) sW3b[t] = (nn < 9) ? f2b(w3[e * 288 + k * 9 + nn]) : (short)0;
  }
  if (t < 64) sB1[t] = db1[e * 64 + t];
  if (t >= 64 && t < 96) sB2[t - 64] = b2[e * 32 + (t - 64)];
  __syncthreads();

  const int wv = t >> 6, lane = t & 63;
  const int q = lane >> 4, m16 = lane & 15;

  // ---- phase A compute: d1 conv ----
  {
    const int octile = wv & 3, mh2 = wv >> 2;
    const int ocl = octile * 16 + m16;
    const int nmA = (mh2 == 0) ? 7 : 6;   // mt = mh2 + 2*i <= 12

    f32x4 accA[7];
    int abA[7];
    #pragma unroll
    for (int i = 0; i < 7; ++i) {
      accA[i] = (f32x4)0.f;
      int mt = mh2 + 2 * i; if (mt > 12) mt = 12;
      int p = mt * 16 + m16; if (p > 195) p = 195;
      int y = p / 14, x = p % 14;
      abA[i] = (y * 16 + x) * 40 + q * 8;
    }

    for (int tap = 0; tap < 9; ++tap) {
      const int toff = ((tap / 3) * 16 + (tap % 3)) * 40;
      bf16x8 bfrag = *(const bf16x8*)&sW[tap * 2048 + octile * 512 + lane * 8];
      #pragma unroll
      for (int i = 0; i < 7; ++i) {
        if (i < nmA) {
          bf16x8 afrag = *(const bf16x8*)&sInH[abA[i] + toff];
          accA[i] = __builtin_amdgcn_mfma_f32_16x16x32_bf16(afrag, bfrag, accA[i], 0, 0, 0);
        }
      }
    }
    __syncthreads();   // all phase-A LDS reads done before sD1 overwrites sW

    for (int v = t; v < 1920; v += 512) {
      int bi = v >> 5, j = v & 31;
      int p;
      if (bi < 16) p = bi;
      else if (bi < 32) p = 240 + (bi - 16);
      else if (bi < 46) p = (bi - 31) * 16;
      else p = (bi - 45) * 16 + 15;
      ((unsigned*)&sD1[p * 72])[j] = 0u;
    }
    const float bias = sB1[ocl];
    #pragma unroll
    for (int i = 0; i < 7; ++i) {
      if (i < nmA) {
        int mt = mh2 + 2 * i;
        #pragma unroll
        for (int r = 0; r < 4; ++r) {
          int p = mt * 16 + q * 4 + r;
          if (p < 196) {
            int row = p / 14, col = p % 14;
            sD1[((row + 1) * 16 + col + 1) * 72 + ocl] =
                f2b(elu_f(accA[i][r] + bias));
          }
        }
      }
    }
  }
  __syncthreads();

  // ---- phase B: d23 ----
  const int nt = wv & 1, mh = wv >> 1;     // mh 0..3
  const int ocl = nt * 16 + m16;
  const int nm = (mh == 0) ? 4 : 3;        // conv2 tiles mt = mh + 4*im <= 12

  const bf16x8 b3f = *(const bf16x8*)&sW3b[m16 * 32 + q * 8];

  int mt3[2], ab3[2];
  const int nmt3 = (wv < 5) ? 2 : 1;       // conv3 tiles wv + 8*i <= 12
  #pragma unroll
  for (int i = 0; i < 2; ++i) {
    int mt = wv + 8 * i; if (mt > 12) mt = 12;
    mt3[i] = mt;
    int p = mt * 16 + m16; if (p > 195) p = 195;
    ab3[i] = p * 40 + q * 8;
  }

  int PY[2], PX[2];
  #pragma unroll
  for (int g = 0; g < 2; ++g) {
    int P = t + 512 * g;
    PY[g] = (P < 784) ? P / 28 : -100;
    PX[g] = (P < 784) ? P % 28 : 0;
  }
  float racc[2] = {0.f, 0.f};

  int ab0[4];
  #pragma unroll
  for (int im = 0; im < 4; ++im) {
    int mt = mh + 4 * im;
    int p = mt * 16 + m16; if (p > 195) p = 195;
    int a = p / 14, bb = p % 14;
    ab0[im] = (a * 16 + bb) * 72 + q * 8;
  }

  for (int par = 0; par < 4; ++par) {
    const int py = par >> 1, px = par & 1;

    {
      const unsigned* wc = wcb + ((size_t)e * 4 + par) * 4096;
      unsigned* du = (unsigned*)sU;
      for (int v = t; v < 4096; v += 512) du[v] = wc[v];
    }
    __syncthreads();

    f32x4 acc[4];
    #pragma unroll
    for (int im = 0; im < 4; ++im) acc[im] = (f32x4)0.f;
    const int pbase = (py * 16 + px) * 72;
    for (int s = 0; s < 8; ++s) {
      int tap = s >> 1, h = s & 1;
      int ty = tap >> 1, tx = tap & 1;
      int toff = pbase + (ty * 16 + tx) * 72 + h * 32;
      bf16x8 bfrag = *(const bf16x8*)&sU[s * 1024 + nt * 512 + lane * 8];
      #pragma unroll
      for (int im = 0; im < 4; ++im) {
        if (im < nm) {
          bf16x8 afrag = *(const bf16x8*)&sD1[ab0[im] + toff];
          acc[im] = __builtin_amdgcn_mfma_f32_16x16x32_bf16(afrag, bfrag, acc[im], 0, 0, 0);
        }
      }
    }
    __syncthreads();

    {
      const float bias = sB2[ocl];
      #pragma unroll
      for (int im = 0; im < 4; ++im) {
        if (im < nm) {
          int mt = mh + 4 * im;
          #pragma unroll
          for (int r = 0; r < 4; ++r) {
            int p = mt * 16 + q * 4 + r;
            if (p < 196) sU[p * 40 + ocl] = f2b(elu_f(acc[im][r] + bias));
          }
        }
      }
    }
    __syncthreads();

    #pragma unroll
    for (int i = 0; i < 2; ++i) {
      if (i < nmt3) {
        bf16x8 af = *(const bf16x8*)&sU[ab3[i]];
        f32x4 a3 = (f32x4)0.f;
        a3 = __builtin_amdgcn_mfma_f32_16x16x32_bf16(af, b3f, a3, 0, 0, 0);
        if (m16 < 9) {
          #pragma unroll
          for (int r = 0; r < 4; ++r) {
            int p = mt3[i] * 16 + q * 4 + r;
            if (p < 196) sC[p * 9 + m16] = a3[r];
          }
        }
      }
    }
    __syncthreads();

    #pragma unroll
    for (int g = 0; g < 2; ++g) {
      const int Y = PY[g], X = PX[g];
      if (Y < 0) continue;
      int RS[2]; int nr = 0;
      if ((Y & 1) == py) { RS[0] = Y; nr = 1; }
      else { if (Y > 0) RS[nr++] = Y - 1; if (Y < 27) RS[nr++] = Y + 1; }
      int CS[2]; int nc = 0;
      if ((X & 1) == px) { CS[0] = X; nc = 1; }
      else { if (X > 0) CS[nc++] = X - 1; if (X < 27) CS[nc++] = X + 1; }
      float s = 0.f;
      for (int ir = 0; ir < nr; ++ir) {
        const int R = RS[ir];
        const int a = (R - py) >> 1, ky = R - Y + 1;
        for (int jc = 0; jc < nc; ++jc) {
          const int C = CS[jc];
          const int bq = (C - px) >> 1, kx = C - X + 1;
          s += sC[(a * 14 + bq) * 9 + ky * 3 + kx];
        }
      }
      racc[g] += s;
    }
    __syncthreads();
  }

  const float b3e = b3[e];
  #pragma unroll
  for (int g = 0; g < 2; ++g) {
    int P = t + 512 * g;
    if (P < 784)
      out[OFF_RECON + (size_t)n * 784 + P] = 1.f / (1.f + __expf(-(racc[g] + b3e)));
  }
}

// ---------------------------------------------------------------------------
extern "C" void kernel_launch(void* const* d_in, const int* in_sizes, int n_in,
                              void* d_out, int out_size, void* d_ws, size_t ws_size,
                              hipStream_t stream) {
  const float* x    = (const float*)d_in[0];
  const float* eps  = (const float*)d_in[1];
  const float* ew1  = (const float*)d_in[2];
  const float* eb1  = (const float*)d_in[3];
  const float* ew2  = (const float*)d_in[4];
  const float* eb2  = (const float*)d_in[5];
  const float* ew3  = (const float*)d_in[6];
  const float* eb3  = (const float*)d_in[7];
  const float* wmu  = (const float*)d_in[8];
  const float* bmu  = (const float*)d_in[9];
  const float* wlv  = (const float*)d_in[10];
  const float* blv  = (const float*)d_in[11];
  const float* gw1  = (const float*)d_in[12];
  const float* gb1  = (const float*)d_in[13];
  const float* gw2  = (const float*)d_in[14];
  const float* gb2  = (const float*)d_in[15];
  const float* gw3  = (const float*)d_in[16];
  const float* gb3  = (const float*)d_in[17];
  const float* dfcw = (const float*)d_in[18];
  const float* dfcb = (const float*)d_in[19];
  const float* dw1  = (const float*)d_in[20];
  const float* db1  = (const float*)d_in[21];
  const float* dw2  = (const float*)d_in[22];
  const float* db2  = (const float*)d_in[23];
  const float* dw3  = (const float*)d_in[24];
  const float* db3  = (const float*)d_in[25];

  float* out = (float*)d_out;
  float* ws  = (float*)d_ws;

  float* U    = ws + WS_U;
  float* zb   = ws + WS_Z;
  int*   idx  = (int*)(ws + WS_IDX);
  unsigned* hfcb = (unsigned*)(U + HFC_OFF);
  unsigned short* w1b = (unsigned short*)(U + W1B_OFF);
  unsigned short* wcb = (unsigned short*)(U + WCB_OFF);
  unsigned short* w2s = (unsigned short*)(ws + WS_WENC + W2S_OFF);
  unsigned short* w3s = (unsigned short*)(ws + WS_WENC + W3S_OFF);
  unsigned* wfc = (unsigned*)(ws + WS_WENC + WFC_OFF);

  k_prep_enc<<<3496, 256, 0, stream>>>(ew2, ew3, wmu, wlv, w2s, w3s, wfc);
  k_enc   <<<NB, 1024, 0, stream>>>(x, ew1, eb1, eb2, w2s, w3s, eb3, (unsigned*)U);
  k_fc    <<<dim3(32, 8), 256, 0, stream>>>((const unsigned*)U, wfc, U);
  k_gate  <<<512, 256, 0, stream>>>(U, bmu, blv, eps, gw1, gb1, gw2, gb2, gw3, gb3,
                                    out, zb, idx);
  k_prep  <<<dim3(8, 5), 256, 0, stream>>>(dw1, dw2, w1b, wcb);
  k_dfc   <<<NB, 256, 0, stream>>>(zb, idx, dfcw, dfcb, hfcb);
  k_dec   <<<NB, 512, 0, stream>>>(hfcb, idx, (const unsigned*)w1b, db1,
                                   (const unsigned*)wcb, db2, dw3, db3, out);
}

// Round 17
// 515.115 us; speedup vs baseline: 1.3284x; 1.3284x over previous
//
#include <hip/hip_runtime.h>
#include <hip/hip_bf16.h>

// ---------------------------------------------------------------------------
// VAE + supervised MoE forward, MI355X.  (R15 best-verified configuration)
//   k_prep_enc: one-time bf16 dual-split pack of encoder conv2/conv3 weights
//               AND fc weight pack [w_mu|w_lv]
//   k_enc    : FUSED encoder conv1+conv2+conv3, one sample per block,
//              512 threads / 8 waves; h2 in LDS; h3 RNE dual-packed.
//              h1 packed RNE dual (h,h,m,0).
//   k_fc     : MFMA slot-split GEMM, LDS-free, K-split 8, partials into U
//   k_gate   : one wave per sample, lane-parallel, shfl softmax/argmax
//   k_prep   : decoder weight repack to bf16, FRAGMENT-LINEAR order
//   k_dfc    : z @ d_fc_w[e] + b -> hfcb bf16
//   k_dec    : FUSED decoder conv1+conv2+conv3, one sample per block
// ---------------------------------------------------------------------------

#define NB 2048

typedef short bf16x8 __attribute__((ext_vector_type(8)));
typedef float f32x4  __attribute__((ext_vector_type(4)));
typedef unsigned u32x4 __attribute__((ext_vector_type(4)));

static constexpr int OFF_RECON  = 0;
static constexpr int OFF_MU     = 1605632;
static constexpr int OFF_LV     = 1736704;
static constexpr int OFF_LOGITS = 1867776;
static constexpr int OFF_PROBS  = 1884160;

// workspace layout (float units)
static constexpr size_t WS_U    = 0;         // 25,690,112 fl (2048 x 12544)
static constexpr size_t WS_Z    = 25690112;  // 131,072 fl
static constexpr size_t WS_IDX  = 25821184;  // 2,048 ints = 512 fl
static constexpr size_t WS_WENC = 25821696;  // packed weights
static constexpr size_t W2S_OFF = 0;         // 36,864 fl
static constexpr size_t W3S_OFF = 36864;     // 147,456 fl
static constexpr size_t WFC_OFF = 184320;    // 802,816 fl (fc (h,m) pack)
static constexpr size_t HFC_OFF = 0;         // hfcb bf16 [n][49][32] in U
static constexpr size_t W1B_OFF = 17000448;  // U tail (written after k_gate)
static constexpr size_t WCB_OFF = 17074176;  // U tail

__device__ __forceinline__ float relu_f(float v) { return v > 0.f ? v : 0.f; }
// branchless ELU: exact for v>=0 (exp(0)==1), error ~3e-8 abs for tiny v<0
__device__ __forceinline__ float elu_f(float v)  {
  return __expf(fminf(v, 0.f)) - 1.f + fmaxf(v, 0.f);
}
__device__ __forceinline__ short f2b(float v) {
  __hip_bfloat16 h = __float2bfloat16(v);
  short s; __builtin_memcpy(&s, &h, 2); return s;
}
__device__ __forceinline__ float s2f(short s) {
  unsigned v = ((unsigned)(unsigned short)s) << 16;
  float f; __builtin_memcpy(&f, &v, 4); return f;
}
// RNE dual pack: v -> (h16 | m16<<16)
__device__ __forceinline__ unsigned pack2(float v) {
  short h = f2b(v);
  short m = f2b(v - s2f(h));
  return (unsigned)(unsigned short)h | ((unsigned)(unsigned short)m << 16);
}

// ---------------------------------------------------------------------------
// one-time weight packs (encoder + fc).
// ---------------------------------------------------------------------------
__global__ __launch_bounds__(256) void k_prep_enc(
    const float* __restrict__ ew2, const float* __restrict__ ew3,
    const float* __restrict__ wmu, const float* __restrict__ wlv,
    unsigned short* __restrict__ w2s, unsigned short* __restrict__ w3s,
    unsigned* __restrict__ wfc)
{
  const int u = blockIdx.x * 256 + threadIdx.x;
  if (u >= 894976) return;
  if (u >= 92160) {
    const int u2 = u - 92160;
    const int kp = u2 >> 8, r = u2 & 255;
    const int n = r >> 1, j = r & 1;
    const int k = kp * 2 + j;
    const float w = (n < 64) ? wmu[k * 64 + n] : wlv[k * 64 + (n - 64)];
    short h = f2b(w);
    short mm = f2b(w - s2f(h));
    wfc[u2] = (unsigned)(unsigned short)h | ((unsigned)(unsigned short)mm << 16);
    return;
  }
  float w; uint2* dst;
  if (u < 18432) {
    int ic = u & 7, oc = (u >> 3) & 63;
    int r = u >> 9;           // chunk*9 + tap
    int tap = r % 9, chunk = r / 9;
    w = ew2[oc * 288 + (chunk * 8 + ic) * 9 + tap];
    dst = (uint2*)w2s + u;
  } else {
    int u2 = u - 18432;
    int ic = u2 & 7, oc = (u2 >> 3) & 127;
    int r = u2 >> 10;         // chunk*9 + tap
    int tap = r % 9, chunk = r / 9;
    w = ew3[oc * 576 + (chunk * 8 + ic) * 9 + tap];
    dst = (uint2*)w3s + u2;
  }
  short h = f2b(w);
  short mm = f2b(w - s2f(h));
  uint2 pk;
  pk.x = (unsigned)(unsigned short)h | ((unsigned)(unsigned short)mm << 16);
  pk.y = (unsigned)(unsigned short)h | ((unsigned)(unsigned short)h << 16);
  *dst = pk;
}

// ---------------------------------------------------------------------------
// FUSED encoder: conv1 + conv2 + conv3, one sample per block, 512 thr/8 wv.
// R11 row-major staging layout. h1 RNE dual-split (h,h,m,0).
// ---------------------------------------------------------------------------
__global__ __launch_bounds__(512, 4) void k_enc(
    const float* __restrict__ x,
    const float* __restrict__ w1, const float* __restrict__ b1,
    const float* __restrict__ b2g, const unsigned short* __restrict__ w2s,
    const unsigned short* __restrict__ w3s, const float* __restrict__ b3,
    unsigned* __restrict__ hb)
{
  __shared__ float sX[900];
  __shared__ float sB2[64];
  __shared__ float sB3[128];
  __shared__ __align__(16) short sH[36000];   // 72,000 B union

  const int n = blockIdx.x, t = threadIdx.x;

  for (int idx = t; idx < 900; idx += 512) {
    int yy = idx / 30, xx = idx % 30;
    float v = 0.f;
    if (yy >= 1 && yy <= 28 && xx >= 1 && xx <= 28)
      v = x[n * 784 + (yy - 1) * 28 + (xx - 1)];
    sX[idx] = v;
  }
  if (t < 64) sB2[t] = b2g[t];
  if (t >= 64 && t < 192) sB3[t - 64] = b3[t - 64];
  for (int bi = t; bi < 116; bi += 512) {
    int p;
    if (bi < 30) p = bi;
    else if (bi < 60) p = 870 + (bi - 30);
    else if (bi < 88) p = (bi - 59) * 30;
    else p = (bi - 87) * 30 + 29;
    unsigned* d = (unsigned*)&sH[p * 40];
    #pragma unroll
    for (int j = 0; j < 20; ++j) d[j] = 0u;
  }
  __syncthreads();

  float xw[2][9];
  int hp[2]; bool pvld[2];
  #pragma unroll
  for (int i = 0; i < 2; ++i) {
    int p = t + 512 * i;
    pvld[i] = (p < 784);
    int yy = pvld[i] ? p / 28 : 0, xx = pvld[i] ? p % 28 : 0;
    hp[i] = (yy + 1) * 30 + xx + 1;
    #pragma unroll
    for (int k = 0; k < 9; ++k)
      xw[i][k] = sX[(yy + k / 3) * 30 + xx + (k % 3)];
  }

  const int lane = t & 63, wv = t >> 6;
  const int q = lane >> 4, m16 = lane & 15;
  const int nth = wv & 1, mh = wv >> 1;          // mh 0..3
  const int nm = (mh == 0) ? 4 : 3;              // conv2 tiles mt 0..12

  int abase[4];
  #pragma unroll
  for (int mtl = 0; mtl < 4; ++mtl) {
    int m = (mh + 4 * mtl) * 16 + m16; if (m > 195) m = 195;
    int yy = m / 14, xx = m % 14;
    abase[mtl] = (yy * 60 + xx * 2) * 40 + q * 8;
  }
  f32x4 acc[4][2];
  #pragma unroll
  for (int a = 0; a < 4; ++a) { acc[a][0] = (f32x4)0.f; acc[a][1] = (f32x4)0.f; }

  // ---- conv1 + conv2 (4 ic-chunks). h1 RNE dual-split (h,h,m,0). ----
  for (int c = 0; c < 4; ++c) {
    #pragma unroll
    for (int o = 0; o < 8; ++o) {
      const int oc = c * 8 + o;
      float wr[9];
      #pragma unroll
      for (int k = 0; k < 9; ++k) wr[k] = w1[oc * 9 + k];
      const float bb = b1[oc];
      #pragma unroll
      for (int i = 0; i < 2; ++i) if (pvld[i]) {
        float v = bb;
        #pragma unroll
        for (int k = 0; k < 9; ++k) v += xw[i][k] * wr[k];
        v = relu_f(v);
        short h = f2b(v);
        short mm = f2b(v - s2f(h));
        uint2 pk;
        pk.x = (unsigned)(unsigned short)h | ((unsigned)(unsigned short)h << 16);
        pk.y = (unsigned)(unsigned short)mm;
        *(uint2*)&sH[hp[i] * 40 + o * 4] = pk;
      }
    }
    __syncthreads();

    const unsigned short* wb = w2s + (size_t)c * 18432;
    for (int tap = 0; tap < 9; ++tap) {
      const int toff = ((tap / 3) * 30 + (tap % 3)) * 40;
      bf16x8 A[4];
      #pragma unroll
      for (int mtl = 0; mtl < 4; ++mtl)
        A[mtl] = *(const bf16x8*)&sH[abase[mtl] + toff];
      #pragma unroll
      for (int ntl = 0; ntl < 2; ++ntl) {
        const int ocl = nth * 32 + ntl * 16 + m16;
        bf16x8 B = *(const bf16x8*)&wb[(tap * 64 + ocl) * 32 + q * 8];
        #pragma unroll
        for (int mtl = 0; mtl < 4; ++mtl)
          if (mtl < nm)
            acc[mtl][ntl] = __builtin_amdgcn_mfma_f32_16x16x32_bf16(A[mtl], B, acc[mtl][ntl], 0, 0, 0);
      }
    }
    __syncthreads();
  }

  // ---- h2 -> LDS packed [196][65] (reuses sH); zero conv3 sIn borders ----
  unsigned* h2p = (unsigned*)sH;
  short* sIn = sH + 25600;
  #pragma unroll
  for (int mtl = 0; mtl < 4; ++mtl) {
    if (mtl < nm) {
      const int mt = mh + 4 * mtl;
      #pragma unroll
      for (int ntl = 0; ntl < 2; ++ntl) {
        const int oc = nth * 32 + ntl * 16 + m16;
        const float bb = sB2[oc];
        #pragma unroll
        for (int r = 0; r < 4; ++r) {
          int p = mt * 16 + q * 4 + r;
          if (p < 196)
            h2p[p * 65 + oc] = pack2(relu_f(acc[mtl][ntl][r] + bb));
        }
      }
    }
  }
  for (int bi = t; bi < 60; bi += 512) {
    int p;
    if (bi < 16) p = bi;
    else if (bi < 32) p = 240 + (bi - 16);
    else if (bi < 46) p = (bi - 31) * 16;
    else p = (bi - 45) * 16 + 15;
    unsigned* d = (unsigned*)&sIn[p * 40];
    #pragma unroll
    for (int j = 0; j < 20; ++j) d[j] = 0u;
  }

  // ---- conv3: 8 ic-chunks, wave = one 16-oc tile, 4 m-tiles ----
  const int oc3 = wv * 16 + m16;
  int abase3[4];
  #pragma unroll
  for (int mtl = 0; mtl < 4; ++mtl) {
    int m = mtl * 16 + m16; if (m > 48) m = 48;
    int yy = m / 7, xx = m % 7;
    abase3[mtl] = (yy * 32 + xx * 2) * 40 + q * 8;
  }
  f32x4 acc3[4];
  #pragma unroll
  for (int a = 0; a < 4; ++a) acc3[a] = (f32x4)0.f;

  for (int c = 0; c < 8; ++c) {
    __syncthreads();
    if (t < 392) {
      int pix = t >> 1, icoff = (t & 1) * 4;
      int rr = pix / 14 + 1, cc = pix % 14 + 1;
      short* drow = &sIn[(rr * 16 + cc) * 40 + icoff * 4];
      #pragma unroll
      for (int i = 0; i < 4; ++i) {
        unsigned u = h2p[pix * 65 + c * 8 + icoff + i];   // h16 | m16<<16
        uint2 pk;
        pk.x = (u << 16) | (u & 0xffffu);                 // (low=h, high=h)
        pk.y = u >> 16;                                   // (low=m, high=0)
        *(uint2*)&drow[i * 4] = pk;
      }
    }
    __syncthreads();

    const unsigned short* wc = w3s + (size_t)c * 36864;
    for (int tap = 0; tap < 9; ++tap) {
      const int toff = ((tap / 3) * 16 + (tap % 3)) * 40;
      bf16x8 B = *(const bf16x8*)&wc[(tap * 128 + oc3) * 32 + q * 8];
      #pragma unroll
      for (int mtl = 0; mtl < 4; ++mtl) {
        bf16x8 A = *(const bf16x8*)&sIn[abase3[mtl] + toff];
        acc3[mtl] = __builtin_amdgcn_mfma_f32_16x16x32_bf16(A, B, acc3[mtl], 0, 0, 0);
      }
    }
  }

  // ---- h3 epilogue: relu + RNE dual pack -> global ----
  const float bb3 = sB3[oc3];
  #pragma unroll
  for (int mtl = 0; mtl < 4; ++mtl) {
    #pragma unroll
    for (int r = 0; r < 4; ++r) {
      int m = mtl * 16 + q * 4 + r;
      if (m < 49)
        hb[(size_t)n * 12544 + oc3 * 49 + m] = pack2(relu_f(acc3[mtl][r] + bb3));
    }
  }
}

// ---------------------------------------------------------------------------
// fc via slot-split MFMA, LDS-free. K-split 8, partials into U upper halves.
// ---------------------------------------------------------------------------
__global__ __launch_bounds__(256) void k_fc(
    const unsigned* __restrict__ A2,
    const unsigned* __restrict__ wfc,
    float* __restrict__ Uf)
{
  const int t = threadIdx.x;
  const int lane = t & 63, wv = t >> 6;
  const int q = lane >> 4, m16 = lane & 15;
  const int m0 = blockIdx.x * 64;
  const int s  = blockIdx.y;

  const unsigned* arow[4];
  #pragma unroll
  for (int mt = 0; mt < 4; ++mt)
    arow[mt] = A2 + (size_t)(m0 + mt * 16 + m16) * 12544 + s * 784 + 2 * q;
  const unsigned* brow[2];
  #pragma unroll
  for (int ntl = 0; ntl < 2; ++ntl)
    brow[ntl] = wfc + (size_t)(s * 392 + q) * 256 + ((wv * 2 + ntl) * 16 + m16) * 2;

  f32x4 acc[4][2];
  #pragma unroll
  for (int a = 0; a < 4; ++a) { acc[a][0] = (f32x4)0.f; acc[a][1] = (f32x4)0.f; }

  #pragma unroll 2
  for (int kt = 0; kt < 98; ++kt) {
    bf16x8 Af[4];
    #pragma unroll
    for (int mt = 0; mt < 4; ++mt) {
      uint2 u = *(const uint2*)(arow[mt] + kt * 8);
      u32x4 w = { (u.x << 16) | (u.x & 0xffffu), u.x >> 16,
                  (u.y << 16) | (u.y & 0xffffu), u.y >> 16 };
      Af[mt] = __builtin_bit_cast(bf16x8, w);
    }
    #pragma unroll
    for (int ntl = 0; ntl < 2; ++ntl) {
      uint2 u = *(const uint2*)(brow[ntl] + kt * 1024);
      u32x4 w = { u.x, (u.x << 16) | (u.x & 0xffffu),
                  u.y, (u.y << 16) | (u.y & 0xffffu) };
      bf16x8 Bf = __builtin_bit_cast(bf16x8, w);
      #pragma unroll
      for (int mt = 0; mt < 4; ++mt)
        acc[mt][ntl] = __builtin_amdgcn_mfma_f32_16x16x32_bf16(Af[mt], Bf, acc[mt][ntl], 0, 0, 0);
    }
  }

  #pragma unroll
  for (int mt = 0; mt < 4; ++mt) {
    #pragma unroll
    for (int ntl = 0; ntl < 2; ++ntl) {
      const int n = (wv * 2 + ntl) * 16 + m16;
      #pragma unroll
      for (int r = 0; r < 4; ++r) {
        const int row = m0 + mt * 16 + q * 4 + r;
        Uf[(size_t)row * 12544 + 6272 + s * 128 + n] = acc[mt][ntl][r];
      }
    }
  }
}

// ---------------------------------------------------------------------------
// gate (fp32), ONE WAVE PER SAMPLE. 512 blocks x 256 threads (4 waves).
// ---------------------------------------------------------------------------
__global__ __launch_bounds__(256) void k_gate(
    const float* __restrict__ Ubase,
    const float* __restrict__ b_mu, const float* __restrict__ b_lv,
    const float* __restrict__ eps,
    const float* __restrict__ gw1, const float* __restrict__ gb1,
    const float* __restrict__ gw2, const float* __restrict__ gb2,
    const float* __restrict__ gw3, const float* __restrict__ gb3,
    float* __restrict__ out, float* __restrict__ zbuf, int* __restrict__ idxbuf)
{
  __shared__ float sZ[4][64];
  __shared__ float sG1[4][64];
  __shared__ float sG2[4][32];
  const int t = threadIdx.x;
  const int wv = t >> 6, lane = t & 63;
  const int m = blockIdx.x * 4 + wv;
  const float* __restrict__ Up = Ubase + (size_t)m * 12544 + 6272;

  {
    const int k = lane;
    float mu = b_mu[k], lv = b_lv[k];
    #pragma unroll
    for (int s8 = 0; s8 < 8; ++s8) {
      mu += Up[s8 * 128 + k];
      lv += Up[s8 * 128 + 64 + k];
    }
    out[OFF_MU + m * 64 + k] = mu;
    out[OFF_LV + m * 64 + k] = lv;
    float zz = mu + eps[m * 64 + k] * expf(0.5f * lv);
    sZ[wv][k] = zz;
    zbuf[m * 64 + k] = zz;
  }

  {
    const int j = lane;
    float a = gb1[j];
    for (int k = 0; k < 64; ++k) a += sZ[wv][k] * gw1[k * 64 + j];
    sG1[wv][j] = relu_f(a);
  }
  if (lane < 32) {
    const int j = lane;
    float a = gb2[j];
    for (int k = 0; k < 64; ++k) a += sG1[wv][k] * gw2[k * 32 + j];
    sG2[wv][j] = relu_f(a);
  }
  float l = -1e30f;
  if (lane < 8) {
    float a = gb3[lane];
    for (int k = 0; k < 32; ++k) a += sG2[wv][k] * gw3[k * 8 + lane];
    l = a;
  }
  float mx = l;
  #pragma unroll
  for (int off = 4; off; off >>= 1) mx = fmaxf(mx, __shfl_xor(mx, off, 8));
  float p = expf(l - mx);
  float ssum = p;
  #pragma unroll
  for (int off = 4; off; off >>= 1) ssum += __shfl_xor(ssum, off, 8);
  float pj = p / ssum;
  if (lane < 8) {
    out[OFF_PROBS + m * 8 + lane] = pj;
    out[OFF_LOGITS + m * 8 + lane] = logf(pj + 1e-8f);
  }
  float pmax = pj;
  #pragma unroll
  for (int off = 4; off; off >>= 1) pmax = fmaxf(pmax, __shfl_xor(pmax, off, 8));
  unsigned long long msk = __ballot(lane < 8 && pj == pmax);
  if (lane == 0) idxbuf[m] = __ffsll(msk) - 1;
}

// ---------------------------------------------------------------------------
// one-time decoder weight repack to bf16, FRAGMENT-LINEAR order.
// ---------------------------------------------------------------------------
__global__ __launch_bounds__(256) void k_prep(
    const float* __restrict__ dw1, const float* __restrict__ dw2,
    unsigned short* __restrict__ w1b, unsigned short* __restrict__ wcb)
{
  const int e = blockIdx.x, job = blockIdx.y, t = threadIdx.x;
  if (job == 0) {
    for (int idx = t; idx < 18432; idx += 256) {
      int tap = idx >> 11;
      int rem = idx & 2047;
      int octile = rem >> 9;
      int lane = (rem >> 3) & 63;
      int j = idx & 7;
      int oc = octile * 16 + (lane & 15);
      int ic = (lane >> 4) * 8 + j;
      w1b[(size_t)e * 18432 + idx] =
          (unsigned short)f2b(dw1[(size_t)e * 18432 + (oc * 32 + ic) * 9 + tap]);
    }
  } else {
    const int par = job - 1, py = par >> 1, px = par & 1;
    for (int v = t; v < 8192; v += 256) {
      int s = v >> 10;
      int nt = (v >> 9) & 1;
      int lane = (v >> 3) & 63;
      int j = v & 7;
      int oc = nt * 16 + (lane & 15);
      int tap = s >> 1, h = s & 1;
      int ty = tap >> 1, tx = tap & 1;
      int icg = h * 32 + (lane >> 4) * 8 + j;
      int ys = (ty == 0) ? 0 : (1 + py);
      int yc = (ty == py) ? 1 : 2;
      int xs = (tx == 0) ? 0 : (1 + px);
      int xc = (tx == px) ? 1 : 2;
      const float* wp = &dw2[(size_t)e * 18432 + (oc * 64 + icg) * 9];
      float a = 0.f;
      for (int ky = ys; ky < ys + yc; ++ky)
        for (int kx = xs; kx < xs + xc; ++kx)
          a += wp[ky * 3 + kx];
      wcb[((size_t)e * 4 + par) * 8192 + v] = (unsigned short)f2b(a);
    }
  }
}

// ---------------------------------------------------------------------------
// decoder fc: z[64] @ d_fc_w[e][64][1568] + b -> hfcb bf16 [n][pix49][ic32]
// ---------------------------------------------------------------------------
__global__ __launch_bounds__(256) void k_dfc(
    const float* __restrict__ zbuf, const int* __restrict__ idxbuf,
    const float* __restrict__ fcw, const float* __restrict__ fcb,
    unsigned* __restrict__ hfcb)
{
  __shared__ float sZ[64];
  __shared__ __align__(16) unsigned short sO[1568];
  const int n = blockIdx.x, t = threadIdx.x;
  const int e = idxbuf[n];
  if (t < 64) sZ[t] = zbuf[n * 64 + t];
  __syncthreads();
  const float* __restrict__ W = fcw + (size_t)e * 100352;
  const int i40 = t, i41 = t + 256;
  const bool v1 = (i41 < 392);
  float a0[4], a1[4];
  {
    float4 b0 = *(const float4*)&fcb[e * 1568 + i40 * 4];
    a0[0] = b0.x; a0[1] = b0.y; a0[2] = b0.z; a0[3] = b0.w;
    if (v1) {
      float4 b1v = *(const float4*)&fcb[e * 1568 + i41 * 4];
      a1[0] = b1v.x; a1[1] = b1v.y; a1[2] = b1v.z; a1[3] = b1v.w;
    } else { a1[0] = a1[1] = a1[2] = a1[3] = 0.f; }
  }
  for (int k = 0; k < 64; ++k) {
    const float zk = sZ[k];
    float4 w0 = *(const float4*)&W[k * 1568 + i40 * 4];
    a0[0] += zk * w0.x; a0[1] += zk * w0.y; a0[2] += zk * w0.z; a0[3] += zk * w0.w;
    if (v1) {
      float4 w1v = *(const float4*)&W[k * 1568 + i41 * 4];
      a1[0] += zk * w1v.x; a1[1] += zk * w1v.y; a1[2] += zk * w1v.z; a1[3] += zk * w1v.w;
    }
  }
  #pragma unroll
  for (int c = 0; c < 4; ++c) {
    int j = i40 * 4 + c;
    int ic = j / 49, p = j % 49;
    sO[p * 32 + ic] = (unsigned short)f2b(a0[c]);
  }
  if (v1) {
    #pragma unroll
    for (int c = 0; c < 4; ++c) {
      int j = i41 * 4 + c;
      int ic = j / 49, p = j % 49;
      sO[p * 32 + ic] = (unsigned short)f2b(a1[c]);
    }
  }
  __syncthreads();
  for (int idx = t; idx < 784; idx += 256)
    hfcb[(size_t)n * 784 + idx] = ((const unsigned*)sO)[idx];
}

// ---------------------------------------------------------------------------
// FUSED decoder: d1 + d23, one sample per block, 512 threads / 8 waves.
// ---------------------------------------------------------------------------
__global__ __launch_bounds__(512, 4) void k_dec(
    const unsigned* __restrict__ hfcb, const int* __restrict__ idxbuf,
    const unsigned* __restrict__ w1b, const float* __restrict__ db1,
    const unsigned* __restrict__ wcb, const float* __restrict__ b2,
    const float* __restrict__ w3, const float* __restrict__ b3,
    float* __restrict__ out)
{
  __shared__ __align__(16) short sPool[32712];
  __shared__ float sB1[64];
  __shared__ float sB2[32];

  short* sInH  = sPool;            // phase A input (256x40)
  short* sW    = sPool + 10240;    // phase A weights (9216 uints)
  short* sD1   = sPool + 10240;    // phase B haloed d1 output (256x72)
  short* sU    = sPool;            // phase B conv2 weights/act (8192 shorts)
  short* sW3b  = sPool + 28672;    // 512 shorts
  float* sC    = (float*)(sPool + 29184);  // 196*9 floats

  const int n = blockIdx.x, t = threadIdx.x;
  const int e = idxbuf[n];

  // ---- phase A staging ----
  {
    int cell = t >> 1, half = t & 1;
    int r = cell >> 4, c = cell & 15;
    bool inter = (r >= 1 && r <= 14 && c >= 1 && c <= 14);
    int src = inter ? (((r - 1) >> 1) * 7 + ((c - 1) >> 1)) : 0;
    const unsigned* hp = &hfcb[(size_t)n * 784 + src * 16 + half * 8];
    unsigned* dst = (unsigned*)&sInH[cell * 40] + half * 8;
    #pragma unroll
    for (int i = 0; i < 8; ++i) dst[i] = inter ? hp[i] : 0u;
  }
  {
    const unsigned* wsrc = w1b + (size_t)e * 9216;
    unsigned* wd = (unsigned*)sW;
    for (int idx = t; idx < 9216; idx += 512) wd[idx] = wsrc[idx];
  }
  {
    int nn = t >> 5, k = t & 31;
    if (t < 512) sW3b[t] = (nn < 9) ? f2b(w3[e * 288 + k * 9 + nn]) : (short)0;
  }
  if (t < 64) sB1[t] = db1[e * 64 + t];
  if (t >= 64 && t < 96) sB2[t - 64] = b2[e * 32 + (t - 64)];
  __syncthreads();

  const int wv = t >> 6, lane = t & 63;
  const int q = lane >> 4, m16 = lane & 15;

  // ---- phase A compute: d1 conv ----
  {
    const int octile = wv & 3, mh2 = wv >> 2;
    const int ocl = octile * 16 + m16;
    const int nmA = (mh2 == 0) ? 7 : 6;   // mt = mh2 + 2*i <= 12

    f32x4 accA[7];
    int abA[7];
    #pragma unroll
    for (int i = 0; i < 7; ++i) {
      accA[i] = (f32x4)0.f;
      int mt = mh2 + 2 * i; if (mt > 12) mt = 12;
      int p = mt * 16 + m16; if (p > 195) p = 195;
      int y = p / 14, x = p % 14;
      abA[i] = (y * 16 + x) * 40 + q * 8;
    }

    for (int tap = 0; tap < 9; ++tap) {
      const int toff = ((tap / 3) * 16 + (tap % 3)) * 40;
      bf16x8 bfrag = *(const bf16x8*)&sW[tap * 2048 + octile * 512 + lane * 8];
      #pragma unroll
      for (int i = 0; i < 7; ++i) {
        if (i < nmA) {
          bf16x8 afrag = *(const bf16x8*)&sInH[abA[i] + toff];
          accA[i] = __builtin_amdgcn_mfma_f32_16x16x32_bf16(afrag, bfrag, accA[i], 0, 0, 0);
        }
      }
    }
    __syncthreads();   // all phase-A LDS reads done before sD1 overwrites sW

    for (int v = t; v < 1920; v += 512) {
      int bi = v >> 5, j = v & 31;
      int p;
      if (bi < 16) p = bi;
      else if (bi < 32) p = 240 + (bi - 16);
      else if (bi < 46) p = (bi - 31) * 16;
      else p = (bi - 45) * 16 + 15;
      ((unsigned*)&sD1[p * 72])[j] = 0u;
    }
    const float bias = sB1[ocl];
    #pragma unroll
    for (int i = 0; i < 7; ++i) {
      if (i < nmA) {
        int mt = mh2 + 2 * i;
        #pragma unroll
        for (int r = 0; r < 4; ++r) {
          int p = mt * 16 + q * 4 + r;
          if (p < 196) {
            int row = p / 14, col = p % 14;
            sD1[((row + 1) * 16 + col + 1) * 72 + ocl] =
                f2b(elu_f(accA[i][r] + bias));
          }
        }
      }
    }
  }
  __syncthreads();

  // ---- phase B: d23 ----
  const int nt = wv & 1, mh = wv >> 1;     // mh 0..3
  const int ocl = nt * 16 + m16;
  const int nm = (mh == 0) ? 4 : 3;        // conv2 tiles mt = mh + 4*im <= 12

  const bf16x8 b3f = *(const bf16x8*)&sW3b[m16 * 32 + q * 8];

  int mt3[2], ab3[2];
  const int nmt3 = (wv < 5) ? 2 : 1;       // conv3 tiles wv + 8*i <= 12
  #pragma unroll
  for (int i = 0; i < 2; ++i) {
    int mt = wv + 8 * i; if (mt > 12) mt = 12;
    mt3[i] = mt;
    int p = mt * 16 + m16; if (p > 195) p = 195;
    ab3[i] = p * 40 + q * 8;
  }

  int PY[2], PX[2];
  #pragma unroll
  for (int g = 0; g < 2; ++g) {
    int P = t + 512 * g;
    PY[g] = (P < 784) ? P / 28 : -100;
    PX[g] = (P < 784) ? P % 28 : 0;
  }
  float racc[2] = {0.f, 0.f};

  int ab0[4];
  #pragma unroll
  for (int im = 0; im < 4; ++im) {
    int mt = mh + 4 * im;
    int p = mt * 16 + m16; if (p > 195) p = 195;
    int a = p / 14, bb = p % 14;
    ab0[im] = (a * 16 + bb) * 72 + q * 8;
  }

  for (int par = 0; par < 4; ++par) {
    const int py = par >> 1, px = par & 1;

    {
      const unsigned* wc = wcb + ((size_t)e * 4 + par) * 4096;
      unsigned* du = (unsigned*)sU;
      for (int v = t; v < 4096; v += 512) du[v] = wc[v];
    }
    __syncthreads();

    f32x4 acc[4];
    #pragma unroll
    for (int im = 0; im < 4; ++im) acc[im] = (f32x4)0.f;
    const int pbase = (py * 16 + px) * 72;
    for (int s = 0; s < 8; ++s) {
      int tap = s >> 1, h = s & 1;
      int ty = tap >> 1, tx = tap & 1;
      int toff = pbase + (ty * 16 + tx) * 72 + h * 32;
      bf16x8 bfrag = *(const bf16x8*)&sU[s * 1024 + nt * 512 + lane * 8];
      #pragma unroll
      for (int im = 0; im < 4; ++im) {
        if (im < nm) {
          bf16x8 afrag = *(const bf16x8*)&sD1[ab0[im] + toff];
          acc[im] = __builtin_amdgcn_mfma_f32_16x16x32_bf16(afrag, bfrag, acc[im], 0, 0, 0);
        }
      }
    }
    __syncthreads();

    {
      const float bias = sB2[ocl];
      #pragma unroll
      for (int im = 0; im < 4; ++im) {
        if (im < nm) {
          int mt = mh + 4 * im;
          #pragma unroll
          for (int r = 0; r < 4; ++r) {
            int p = mt * 16 + q * 4 + r;
            if (p < 196) sU[p * 40 + ocl] = f2b(elu_f(acc[im][r] + bias));
          }
        }
      }
    }
    __syncthreads();

    #pragma unroll
    for (int i = 0; i < 2; ++i) {
      if (i < nmt3) {
        bf16x8 af = *(const bf16x8*)&sU[ab3[i]];
        f32x4 a3 = (f32x4)0.f;
        a3 = __builtin_amdgcn_mfma_f32_16x16x32_bf16(af, b3f, a3, 0, 0, 0);
        if (m16 < 9) {
          #pragma unroll
          for (int r = 0; r < 4; ++r) {
            int p = mt3[i] * 16 + q * 4 + r;
            if (p < 196) sC[p * 9 + m16] = a3[r];
          }
        }
      }
    }
    __syncthreads();

    #pragma unroll
    for (int g = 0; g < 2; ++g) {
      const int Y = PY[g], X = PX[g];
      if (Y < 0) continue;
      int RS[2]; int nr = 0;
      if ((Y & 1) == py) { RS[0] = Y; nr = 1; }
      else { if (Y > 0) RS[nr++] = Y - 1; if (Y < 27) RS[nr++] = Y + 1; }
      int CS[2]; int nc = 0;
      if ((X & 1) == px) { CS[0] = X; nc = 1; }
      else { if (X > 0) CS[nc++] = X - 1; if (X < 27) CS[nc++] = X + 1; }
      float s = 0.f;
      for (int ir = 0; ir < nr; ++ir) {
        const int R = RS[ir];
        const int a = (R - py) >> 1, ky = R - Y + 1;
        for (int jc = 0; jc < nc; ++jc) {
          const int C = CS[jc];
          const int bq = (C - px) >> 1, kx = C - X + 1;
          s += sC[(a * 14 + bq) * 9 + ky * 3 + kx];
        }
      }
      racc[g] += s;
    }
    __syncthreads();
  }

  const float b3e = b3[e];
  #pragma unroll
  for (int g = 0; g < 2; ++g) {
    int P = t + 512 * g;
    if (P < 784)
      out[OFF_RECON + (size_t)n * 784 + P] = 1.f / (1.f + __expf(-(racc[g] + b3e)));
  }
}

// ---------------------------------------------------------------------------
extern "C" void kernel_launch(void* const* d_in, const int* in_sizes, int n_in,
                              void* d_out, int out_size, void* d_ws, size_t ws_size,
                              hipStream_t stream) {
  const float* x    = (const float*)d_in[0];
  const float* eps  = (const float*)d_in[1];
  const float* ew1  = (const float*)d_in[2];
  const float* eb1  = (const float*)d_in[3];
  const float* ew2  = (const float*)d_in[4];
  const float* eb2  = (const float*)d_in[5];
  const float* ew3  = (const float*)d_in[6];
  const float* eb3  = (const float*)d_in[7];
  const float* wmu  = (const float*)d_in[8];
  const float* bmu  = (const float*)d_in[9];
  const float* wlv  = (const float*)d_in[10];
  const float* blv  = (const float*)d_in[11];
  const float* gw1  = (const float*)d_in[12];
  const float* gb1  = (const float*)d_in[13];
  const float* gw2  = (const float*)d_in[14];
  const float* gb2  = (const float*)d_in[15];
  const float* gw3  = (const float*)d_in[16];
  const float* gb3  = (const float*)d_in[17];
  const float* dfcw = (const float*)d_in[18];
  const float* dfcb = (const float*)d_in[19];
  const float* dw1  = (const float*)d_in[20];
  const float* db1  = (const float*)d_in[21];
  const float* dw2  = (const float*)d_in[22];
  const float* db2  = (const float*)d_in[23];
  const float* dw3  = (const float*)d_in[24];
  const float* db3  = (const float*)d_in[25];

  float* out = (float*)d_out;
  float* ws  = (float*)d_ws;

  float* U    = ws + WS_U;
  float* zb   = ws + WS_Z;
  int*   idx  = (int*)(ws + WS_IDX);
  unsigned* hfcb = (unsigned*)(U + HFC_OFF);
  unsigned short* w1b = (unsigned short*)(U + W1B_OFF);
  unsigned short* wcb = (unsigned short*)(U + WCB_OFF);
  unsigned short* w2s = (unsigned short*)(ws + WS_WENC + W2S_OFF);
  unsigned short* w3s = (unsigned short*)(ws + WS_WENC + W3S_OFF);
  unsigned* wfc = (unsigned*)(ws + WS_WENC + WFC_OFF);

  k_prep_enc<<<3496, 256, 0, stream>>>(ew2, ew3, wmu, wlv, w2s, w3s, wfc);
  k_enc   <<<NB, 512, 0, stream>>>(x, ew1, eb1, eb2, w2s, w3s, eb3, (unsigned*)U);
  k_fc    <<<dim3(32, 8), 256, 0, stream>>>((const unsigned*)U, wfc, U);
  k_gate  <<<512, 256, 0, stream>>>(U, bmu, blv, eps, gw1, gb1, gw2, gb2, gw3, gb3,
                                    out, zb, idx);
  k_prep  <<<dim3(8, 5), 256, 0, stream>>>(dw1, dw2, w1b, wcb);
  k_dfc   <<<NB, 256, 0, stream>>>(zb, idx, dfcw, dfcb, hfcb);
  k_dec   <<<NB, 512, 0, stream>>>(hfcb, idx, (const unsigned*)w1b, db1,
                                   (const unsigned*)wcb, db2, dw3, db3, out);
}